// Round 14
// baseline (2390.848 us; speedup 1.0000x reference)
//
#include <hip/hip_runtime.h>
#include <hip/hip_bf16.h>

#define HD 1024
#define BB 512
#define SS 64
#define N3 3072
#define NC2 7168     // Cbuf cols: [Srz 2048 | gin 1024 | ghn 1024 | gh1 3072]
#define ND 9
#define VC 4
#define KI 832       // padded K for init GEMM (784 -> 13*64)
#define HC 2048      // hcat row stride ([h1b | h2b])

// Wcat2 element offsets
#define WRZ_OFF  0                         // 2048 rows x K=2048
#define WGIN_OFF (2048 * 2048)             // 1024 rows x K=1024
#define WGHN_OFF (WGIN_OFF + 1024 * 1024)  // 1024 rows x K=1024
#define WH1_OFF  (WGHN_OFF + 1024 * 1024)  // 3072 rows x K=1024

typedef __attribute__((ext_vector_type(8))) short bf16x8;
typedef __attribute__((ext_vector_type(4))) float f32x4;

__device__ __forceinline__ ushort f2b(float f) {
    unsigned u = __builtin_bit_cast(unsigned, f);
    u += 0x7fffu + ((u >> 16) & 1u);          // round-to-nearest-even
    return (ushort)(u >> 16);
}

__device__ __forceinline__ float sigf(float x) {
    return 1.f / (1.f + __expf(-x));
}

__device__ __forceinline__ void gld_lds16(const void* g, void* l) {
    __builtin_amdgcn_global_load_lds(
        (const __attribute__((address_space(1))) unsigned int*)g,
        (__attribute__((address_space(3))) unsigned int*)l, 16, 0, 0);
}

// ============================================================================
// prep_w2: build Wcat2.
//  rows 0..2047   : Wrz row j = [W_ih2[j][0..1023] | W_hh2[j][0..1023]] (K=2048)
//  rows 2048..3071: gin row = W_ih2[2048+j]  (K=1024)
//  rows 3072..4095: ghn row = W_hh2[2048+j]  (K=1024)
//  rows 4096..7167: gh1 row = W_hh1[j]       (K=1024)
// grid (7168), 256 thr.
// ============================================================================
__global__ __launch_bounds__(256) void prep_w2(
    const float* __restrict__ Wih2, const float* __restrict__ Whh1,
    const float* __restrict__ Whh2, ushort* __restrict__ Wcat2)
{
    const int row = blockIdx.x;
    const int c = threadIdx.x * 4;
    if (row < 2048) {
        float4 a = *(const float4*)(Wih2 + (size_t)row * HD + c);
        float4 b = *(const float4*)(Whh2 + (size_t)row * HD + c);
        ushort4 oa, ob;
        oa.x = f2b(a.x); oa.y = f2b(a.y); oa.z = f2b(a.z); oa.w = f2b(a.w);
        ob.x = f2b(b.x); ob.y = f2b(b.y); ob.z = f2b(b.z); ob.w = f2b(b.w);
        ushort* dst = Wcat2 + WRZ_OFF + (size_t)row * 2048;
        *(ushort4*)(dst + c)        = oa;
        *(ushort4*)(dst + 1024 + c) = ob;
    } else {
        const float* src;
        ushort* dst;
        if (row < 3072) {        // gin
            src = Wih2 + (size_t)(2048 + row - 2048) * HD + (size_t)(row - 2048) * 0;
            src = Wih2 + (size_t)(row) * HD;             // row in 2048..3071
            dst = Wcat2 + WGIN_OFF + (size_t)(row - 2048) * HD;
        } else if (row < 4096) { // ghn
            src = Whh2 + (size_t)(row - 3072 + 2048) * HD;
            dst = Wcat2 + WGHN_OFF + (size_t)(row - 3072) * HD;
        } else {                 // gh1
            src = Whh1 + (size_t)(row - 4096) * HD;
            dst = Wcat2 + WH1_OFF + (size_t)(row - 4096) * HD;
        }
        float4 v = *(const float4*)(src + c);
        ushort4 o;
        o.x = f2b(v.x); o.y = f2b(v.y); o.z = f2b(v.z); o.w = f2b(v.w);
        *(ushort4*)(dst + c) = o;
    }
}

__global__ __launch_bounds__(256) void prep_wt1(
    const float* __restrict__ Wih1, float* __restrict__ Wt1)
{
    const int g = blockIdx.x * 256 + threadIdx.x;
    #pragma unroll
    for (int c = 0; c < 22; ++c)
        Wt1[c * N3 + g] = Wih1[(size_t)g * 22 + c];
}

__global__ __launch_bounds__(256) void prep_acat(
    const float* __restrict__ z, const float* __restrict__ ne,
    const float* __restrict__ gc, ushort* __restrict__ Acat)
{
    const int b = blockIdx.x;
    const int t = threadIdx.x;
    if (t >= 208) return;
    const int c = t * 4;
    float4 v = make_float4(0.f, 0.f, 0.f, 0.f);
    if (c < 256)      v = *(const float4*)(z  + (size_t)b * 256 + c);
    else if (c < 768) v = *(const float4*)(ne + (size_t)b * 512 + (c - 256));
    else if (c < 784) v = *(const float4*)(gc + (size_t)b * 16  + (c - 768));
    ushort4 o;
    o.x = f2b(v.x); o.y = f2b(v.y); o.z = f2b(v.z); o.w = f2b(v.w);
    *(ushort4*)(Acat + (size_t)b * KI + c) = o;
}

__global__ __launch_bounds__(256) void prep_win(
    const float* __restrict__ W_in, ushort* __restrict__ W_inb)
{
    const int r = blockIdx.x;
    const int t = threadIdx.x;
    if (t >= 208) return;
    const int c = t * 4;
    ushort4 o = {0, 0, 0, 0};
    if (c < 784) {
        float4 v = *(const float4*)(W_in + (size_t)r * 784 + c);
        o.x = f2b(v.x); o.y = f2b(v.y); o.z = f2b(v.z); o.w = f2b(v.w);
    }
    *(ushort4*)(W_inb + (size_t)r * KI + c) = o;
}

// ============================================================================
// k_init: h1 = tanh(Acat @ W_inb^T + b_in). BK=64 dbuf (verified R9-R12).
// Writes h1 f32 (stride 1024) + bf16 shadow into hcat (stride 2048).
// ============================================================================
__global__ __launch_bounds__(256) void k_init(
    const ushort* __restrict__ Acat, const ushort* __restrict__ W_inb,
    const float* __restrict__ b_in, float* __restrict__ h1, ushort* __restrict__ hcat)
{
    __shared__ __align__(16) ushort As[2 * 4096];
    __shared__ __align__(16) ushort Bs[2 * 4096];
    const int t = blockIdx.x;
    const int nt = t >> 3, mt = t & 7;

    const int tid = threadIdx.x;
    const int w = tid >> 6, l = tid & 63;
    const int lr = l >> 3;
    const int sw = ((l & 7) ^ lr) << 3;

    const ushort* Ag0 = Acat + ((size_t)(mt << 6) + 16 * w + lr) * KI + sw;
    const ushort* Ag1 = Ag0 + 8 * KI;
    const ushort* Bg0 = W_inb + ((size_t)(nt << 6) + 16 * w + lr) * KI + sw;
    const ushort* Bg1 = Bg0 + 8 * KI;
    const int o0 = (16 * w) * 64, o1 = (16 * w + 8) * 64;

    gld_lds16(Ag0, As + o0); gld_lds16(Ag1, As + o1);
    gld_lds16(Bg0, Bs + o0); gld_lds16(Bg1, Bs + o1);

    const int wm = (w >> 1) << 5, wn = (w & 1) << 5;
    const int fr = l & 15, fc = l >> 4;
    const int ra0 = wm + fr, ra1 = wm + 16 + fr;
    const int rb0 = wn + fr, rb1 = wn + 16 + fr;

    f32x4 acc[2][2] = {};
    for (int kt = 0; kt < 13; ++kt) {
        const int cb = (kt & 1) << 12;
        __syncthreads();
        if (kt + 1 < 13) {
            const int nb = ((kt + 1) & 1) << 12;
            const int ko = (kt + 1) << 6;
            gld_lds16(Ag0 + ko, As + nb + o0);
            gld_lds16(Ag1 + ko, As + nb + o1);
            gld_lds16(Bg0 + ko, Bs + nb + o0);
            gld_lds16(Bg1 + ko, Bs + nb + o1);
        }
        #pragma unroll
        for (int kk = 0; kk < 2; ++kk) {
            const int c = (kk << 2) + fc;
            bf16x8 a0 = *(const bf16x8*)(As + cb + ra0 * 64 + ((c ^ (ra0 & 7)) << 3));
            bf16x8 a1 = *(const bf16x8*)(As + cb + ra1 * 64 + ((c ^ (ra1 & 7)) << 3));
            bf16x8 b0 = *(const bf16x8*)(Bs + cb + rb0 * 64 + ((c ^ (rb0 & 7)) << 3));
            bf16x8 b1 = *(const bf16x8*)(Bs + cb + rb1 * 64 + ((c ^ (rb1 & 7)) << 3));
            acc[0][0] = __builtin_amdgcn_mfma_f32_16x16x32_bf16(a0, b0, acc[0][0], 0, 0, 0);
            acc[0][1] = __builtin_amdgcn_mfma_f32_16x16x32_bf16(a0, b1, acc[0][1], 0, 0, 0);
            acc[1][0] = __builtin_amdgcn_mfma_f32_16x16x32_bf16(a1, b0, acc[1][0], 0, 0, 0);
            acc[1][1] = __builtin_amdgcn_mfma_f32_16x16x32_bf16(a1, b1, acc[1][1], 0, 0, 0);
        }
    }

    const int row0 = (mt << 6) + wm;
    const int col0 = (nt << 6) + wn + fr;
    const float b0v = b_in[col0], b1v = b_in[col0 + 16];
    #pragma unroll
    for (int i = 0; i < 2; ++i) {
        #pragma unroll
        for (int r = 0; r < 4; ++r) {
            const int row = row0 + i * 16 + fc * 4 + r;
            const float v0 = tanhf(acc[i][0][r] + b0v);
            const float v1 = tanhf(acc[i][1][r] + b1v);
            h1[(size_t)row * HD + col0]        = v0;
            hcat[(size_t)row * HC + col0]      = f2b(v0);
            h1[(size_t)row * HD + col0 + 16]   = v1;
            hcat[(size_t)row * HC + col0 + 16] = f2b(v1);
        }
    }
}

// ============================================================================
// gemm3: Cbuf[512, 7168] sections:
//   sec0 (heavy): Srz = hcat @ Wrz^T       K=2048, 32 local tiles, cols 0..2047
//   sec1: gin = h1b @ Wih2_n^T             K=1024, 16 tiles, cols 2048..3071
//   sec2: ghn = h2b @ Whh2_n^T             K=1024, 16 tiles, cols 3072..4095
//   sec3: gh1 = h1b @ Whh1^T               K=1024, 48 tiles, cols 4096..7167
// R12-EXACT inner loop (64x64 tile, single-buffered 16KB LDS, 2 barriers/iter,
// global_load_lds w16, XOR swizzle). Heavy tiles interleaved 2-of-7 so each
// XCD chunk carries equal work. ntb>=0 => prologue: force sec3, secnt=ntr.
// ============================================================================
__global__ __launch_bounds__(256) void gemm3(
    const ushort* __restrict__ hcat, const ushort* __restrict__ Wcat2,
    float* __restrict__ Cbuf, int ntb)
{
    __shared__ __align__(16) ushort As[4096];   // [64][64] linear
    __shared__ __align__(16) ushort Ws[4096];

    const int flat = blockIdx.x + (blockIdx.y << 3);
    const int id   = (flat & 7) * gridDim.y + (flat >> 3);  // XCD-contiguous
    const int mt   = id & 7;
    const int ntr  = id >> 3;
    const int bm   = mt << 6;

    int kiters, wstride, koff, cbase;
    const ushort* Wb;
    if (ntb >= 0) {                 // prologue: gh1 only
        kiters = 16; wstride = HD; koff = 0;
        Wb = Wcat2 + WH1_OFF + (size_t)(ntr << 6) * HD;
        cbase = 4096 + (ntr << 6);
    } else {
        const int r7 = ntr % 7, q7 = ntr / 7;
        if (r7 == 0 || r7 == 4) {   // heavy: merged rz, K=2048
            const int sn = q7 * 2 + (r7 == 4 ? 1 : 0);     // 0..31
            kiters = 32; wstride = 2048; koff = 0;
            Wb = Wcat2 + WRZ_OFF + (size_t)(sn << 6) * 2048;
            cbase = sn << 6;
        } else {
            const int lr = (r7 < 4) ? (r7 - 1) : (r7 - 2); // 0..4
            const int lidx = q7 * 5 + lr;                   // 0..79
            kiters = 16; wstride = HD;
            if (lidx < 16) {        // gin
                koff = 0;
                Wb = Wcat2 + WGIN_OFF + (size_t)(lidx << 6) * HD;
                cbase = 2048 + (lidx << 6);
            } else if (lidx < 32) { // ghn
                koff = 1024;
                Wb = Wcat2 + WGHN_OFF + (size_t)((lidx - 16) << 6) * HD;
                cbase = 3072 + ((lidx - 16) << 6);
            } else {                // gh1
                koff = 0;
                Wb = Wcat2 + WH1_OFF + (size_t)((lidx - 32) << 6) * HD;
                cbase = 4096 + ((lidx - 32) << 6);
            }
        }
    }

    const int tid = threadIdx.x;
    const int w   = tid >> 6;
    const int l   = tid & 63;

    const int srow = l >> 3;
    const int sch  = ((l & 7) ^ srow) << 3;
    const ushort* Ag0 = hcat + (size_t)(bm + 16 * w + srow) * HC + koff + sch;
    const ushort* Ag1 = Ag0 + 8 * HC;
    const ushort* Wg0 = Wb + (size_t)(16 * w + srow) * wstride + sch;
    const ushort* Wg1 = Wg0 + 8 * wstride;
    ushort* Al0 = As + (16 * w) * 64;
    ushort* Al1 = As + (16 * w + 8) * 64;
    ushort* Wl0 = Ws + (16 * w) * 64;
    ushort* Wl1 = Ws + (16 * w + 8) * 64;

    const int wm = (w >> 1) << 5;
    const int wn = (w & 1) << 5;
    const int fr = l & 15;
    const int fc = l >> 4;

    const int ra0 = wm + fr,  ra1 = wm + 16 + fr;
    const int rb0 = wn + fr,  rb1 = wn + 16 + fr;

    f32x4 acc00 = {0.f,0.f,0.f,0.f}, acc01 = {0.f,0.f,0.f,0.f};
    f32x4 acc10 = {0.f,0.f,0.f,0.f}, acc11 = {0.f,0.f,0.f,0.f};

    for (int kt = 0; kt < kiters; ++kt) {
        const int ko = kt << 6;
        __syncthreads();
        gld_lds16(Ag0 + ko, Al0);
        gld_lds16(Ag1 + ko, Al1);
        gld_lds16(Wg0 + ko, Wl0);
        gld_lds16(Wg1 + ko, Wl1);
        __syncthreads();
        #pragma unroll
        for (int kk = 0; kk < 2; ++kk) {
            const int c = (kk << 2) + fc;
            bf16x8 a0 = *(const bf16x8*)(As + ra0 * 64 + ((c ^ (ra0 & 7)) << 3));
            bf16x8 a1 = *(const bf16x8*)(As + ra1 * 64 + ((c ^ (ra1 & 7)) << 3));
            bf16x8 b0 = *(const bf16x8*)(Ws + rb0 * 64 + ((c ^ (rb0 & 7)) << 3));
            bf16x8 b1 = *(const bf16x8*)(Ws + rb1 * 64 + ((c ^ (rb1 & 7)) << 3));
            acc00 = __builtin_amdgcn_mfma_f32_16x16x32_bf16(a0, b0, acc00, 0, 0, 0);
            acc01 = __builtin_amdgcn_mfma_f32_16x16x32_bf16(a0, b1, acc01, 0, 0, 0);
            acc10 = __builtin_amdgcn_mfma_f32_16x16x32_bf16(a1, b0, acc10, 0, 0, 0);
            acc11 = __builtin_amdgcn_mfma_f32_16x16x32_bf16(a1, b1, acc11, 0, 0, 0);
        }
    }

    float* Cw = Cbuf + (size_t)(bm + wm) * NC2 + cbase + wn;
    #pragma unroll
    for (int r = 0; r < 4; ++r) {
        const size_t ro0 = (size_t)(fc * 4 + r) * NC2;
        const size_t ro1 = (size_t)(16 + fc * 4 + r) * NC2;
        Cw[ro0 + fr]      = acc00[r];
        Cw[ro0 + 16 + fr] = acc01[r];
        Cw[ro1 + fr]      = acc10[r];
        Cw[ro1 + 16 + fr] = acc11[r];
    }
}

// ============================================================================
// gru1_first: step-0 GRU1 (out_prev = 0); writes h1 + hcat[h1b], copies to
// h2 + hcat[h2b]. grid (512) x 1024 threads.
// ============================================================================
__global__ __launch_bounds__(1024) void gru1_first(
    const float* __restrict__ Cbuf, float* __restrict__ h1, float* __restrict__ h2,
    ushort* __restrict__ hcat,
    const float* __restrict__ note, const float* __restrict__ velc,
    const float* __restrict__ Wt1, const float* __restrict__ b_ih1,
    const float* __restrict__ b_hh1)
{
    __shared__ float inp[22];
    const int b = blockIdx.x;
    const int j = threadIdx.x;

    if (j < 22) {
        float v = 0.f;
        if (j >= 9 && j < 18) v = note[(size_t)b * (SS * ND) + (j - 9)];
        else if (j >= 18)     v = velc[(size_t)b * (SS * VC) + (j - 18)];
        inp[j] = v;
    }
    __syncthreads();

    float ir = b_ih1[j], iz = b_ih1[HD + j], inn = b_ih1[2 * HD + j];
    #pragma unroll
    for (int c = 0; c < 22; ++c) {
        const float x = inp[c];
        const float* wr = Wt1 + c * N3;
        ir  = fmaf(x, wr[j],          ir);
        iz  = fmaf(x, wr[HD + j],     iz);
        inn = fmaf(x, wr[2 * HD + j], inn);
    }

    const float* g = Cbuf + (size_t)b * NC2 + 4096;  // gh1 section
    const float hr = g[j]          + b_hh1[j];
    const float hz = g[HD + j]     + b_hh1[HD + j];
    const float hn = g[2 * HD + j] + b_hh1[2 * HD + j];

    const float rg = sigf(ir + hr);
    const float zg = sigf(iz + hz);
    const float n  = tanhf(inn + rg * hn);
    const float hnew = (1.f - zg) * n + zg * h1[(size_t)b * HD + j];
    const ushort hb = f2b(hnew);
    h1[(size_t)b * HD + j]       = hnew;
    h2[(size_t)b * HD + j]       = hnew;
    hcat[(size_t)b * HC + j]     = hb;   // h1b
    hcat[(size_t)b * HC + 1024 + j] = hb; // h2b
}

// ============================================================================
// pw_fused(step): per block TWO batch rows (grid 256 x 1024 thr).
// GRU2 (merged rz) -> h2 + hcat ; out[step] ; GRU1(step+1) -> h1 + hcat.
// ============================================================================
__global__ __launch_bounds__(1024) void pw_fused(
    const float* __restrict__ Cbuf, float* __restrict__ h1, float* __restrict__ h2,
    ushort* __restrict__ hcat,
    const float* __restrict__ note, const float* __restrict__ velc,
    const float* __restrict__ Wt1,
    const float* __restrict__ b_ih1, const float* __restrict__ b_hh1,
    const float* __restrict__ b_ih2, const float* __restrict__ b_hh2,
    const float* __restrict__ W_out, const float* __restrict__ b_out,
    float* __restrict__ dout, int step)
{
    __shared__ float hs[2][HD];
    __shared__ float inp[2][22];
    const int j  = threadIdx.x;
    const int b0 = blockIdx.x * 2;

    // stage next-step note/velc for both rows
    if (step + 1 < SS && j < 64) {
        const int r = j >> 5, c = j & 31;
        const int b = b0 + r;
        if (c >= 9 && c < 22)
            inp[r][c] = (c < 18) ? note[(size_t)b * (SS * ND) + (step + 1) * ND + (c - 9)]
                                 : velc[(size_t)b * (SS * VC) + (step + 1) * VC + (c - 18)];
    }

    const float brz = b_ih2[j]          + b_hh2[j];        // merged r bias
    const float bzz = b_ih2[HD + j]     + b_hh2[HD + j];   // merged z bias
    const float bin = b_ih2[2 * HD + j];
    const float bhn = b_hh2[2 * HD + j];

    #pragma unroll
    for (int r = 0; r < 2; ++r) {
        const int b = b0 + r;
        const float* cb = Cbuf + (size_t)b * NC2;
        const float sr  = cb[j]           + brz;   // Srz r
        const float sz  = cb[1024 + j]    + bzz;   // Srz z
        const float gin = cb[2048 + j]    + bin;
        const float ghn = cb[3072 + j]    + bhn;
        const float rg = sigf(sr);
        const float zg = sigf(sz);
        const float n  = tanhf(gin + rg * ghn);
        const float hnew = (1.f - zg) * n + zg * h2[(size_t)b * HD + j];
        h2[(size_t)b * HD + j] = hnew;
        hcat[(size_t)b * HC + 1024 + j] = f2b(hnew);
        hs[r][j] = hnew;
    }
    __syncthreads();

    // out[b, step, :] — wave w: row r = w&1, dots d = (w>>1) and (w>>1)+8
    const int w = j >> 6, t = j & 63;
    {
        const int r = w & 1, b = b0 + r;
        #pragma unroll
        for (int dd = 0; dd < 2; ++dd) {
            const int d = (w >> 1) + dd * 8;
            if (d < ND) {
                float a = 0.f;
                const float* wr = W_out + (size_t)d * HD;
                #pragma unroll
                for (int k = 0; k < HD / 64; ++k)
                    a = fmaf(hs[r][t + k * 64], wr[t + k * 64], a);
                #pragma unroll
                for (int off = 32; off > 0; off >>= 1) a += __shfl_down(a, off);
                if (t == 0) {
                    const float o = sigf(a + b_out[d]);
                    dout[(size_t)b * (SS * ND) + step * ND + d] = o;
                    inp[r][d] = o;
                }
            }
        }
    }
    __syncthreads();

    // GRU1 for step+1, both rows; Wt1 read once per thread
    if (step + 1 < SS) {
        float xir[2], xiz[2], xinn[2];
        #pragma unroll
        for (int r = 0; r < 2; ++r) {
            xir[r] = b_ih1[j]; xiz[r] = b_ih1[HD + j]; xinn[r] = b_ih1[2 * HD + j];
        }
        #pragma unroll
        for (int c = 0; c < 22; ++c) {
            const float w0 = Wt1[c * N3 + j];
            const float w1 = Wt1[c * N3 + HD + j];
            const float w2 = Wt1[c * N3 + 2 * HD + j];
            #pragma unroll
            for (int r = 0; r < 2; ++r) {
                const float x = inp[r][c];
                xir[r]  = fmaf(x, w0, xir[r]);
                xiz[r]  = fmaf(x, w1, xiz[r]);
                xinn[r] = fmaf(x, w2, xinn[r]);
            }
        }
        #pragma unroll
        for (int r = 0; r < 2; ++r) {
            const int b = b0 + r;
            const float* g1 = Cbuf + (size_t)b * NC2 + 4096;  // gh1 (for step+1)
            const float hr1 = g1[j]          + b_hh1[j];
            const float hz1 = g1[HD + j]     + b_hh1[HD + j];
            const float hn1 = g1[2 * HD + j] + b_hh1[2 * HD + j];
            const float rg1 = sigf(xir[r] + hr1);
            const float zg1 = sigf(xiz[r] + hz1);
            const float n1  = tanhf(xinn[r] + rg1 * hn1);
            const float h1new = (1.f - zg1) * n1 + zg1 * h1[(size_t)b * HD + j];
            h1[(size_t)b * HD + j] = h1new;
            hcat[(size_t)b * HC + j] = f2b(h1new);
        }
    }
}

// ============================================================================
extern "C" void kernel_launch(void* const* d_in, const int* in_sizes, int n_in,
                              void* d_out, int out_size, void* d_ws, size_t ws_size,
                              hipStream_t stream)
{
    const float* z     = (const float*)d_in[0];
    const float* ne    = (const float*)d_in[1];
    const float* note  = (const float*)d_in[3];
    const float* velc  = (const float*)d_in[4];
    const float* gc    = (const float*)d_in[5];
    const float* W_in  = (const float*)d_in[6];
    const float* b_in  = (const float*)d_in[7];
    const float* W_ih1 = (const float*)d_in[8];
    const float* W_hh1 = (const float*)d_in[9];
    const float* b_ih1 = (const float*)d_in[10];
    const float* b_hh1 = (const float*)d_in[11];
    const float* W_ih2 = (const float*)d_in[12];
    const float* W_hh2 = (const float*)d_in[13];
    const float* b_ih2 = (const float*)d_in[14];
    const float* b_hh2 = (const float*)d_in[15];
    const float* W_out = (const float*)d_in[16];
    const float* b_out = (const float*)d_in[17];
    float* out = (float*)d_out;

    // workspace layout (~40 MB)
    float*  h1    = (float*)d_ws;                     // [512*1024]
    float*  h2    = h1 + BB * HD;                     // [512*1024]
    float*  Cbuf  = h2 + BB * HD;                     // [512*7168]
    float*  Wt1   = Cbuf + (size_t)BB * NC2;          // [22*3072]
    ushort* hcat  = (ushort*)(Wt1 + 22 * N3);         // [512*2048]
    ushort* Wcat2 = hcat + (size_t)BB * HC;           // [9437184]
    // init-only buffers aliased into Cbuf (consumed before Cbuf is written)
    ushort* Acat  = (ushort*)Cbuf;                    // [512*832]
    ushort* W_inb = Acat + (size_t)BB * KI;           // [1024*832]

    prep_w2  <<<dim3(NC2), 256, 0, stream>>>(W_ih2, W_hh1, W_hh2, Wcat2);
    prep_wt1 <<<dim3(12),  256, 0, stream>>>(W_ih1, Wt1);
    prep_acat<<<dim3(BB),  256, 0, stream>>>(z, ne, gc, Acat);
    prep_win <<<dim3(HD),  256, 0, stream>>>(W_in, W_inb);

    k_init<<<dim3(128), 256, 0, stream>>>(Acat, W_inb, b_in, h1, hcat);

    // prologue: gh1(0)  (sec3, 48 tiles)
    gemm3<<<dim3(8, 48), 256, 0, stream>>>(hcat, Wcat2, Cbuf, 0);
    gru1_first<<<dim3(BB), 1024, 0, stream>>>(Cbuf, h1, h2, hcat,
                                              note, velc, Wt1, b_ih1, b_hh1);

    for (int s = 0; s < SS; ++s) {
        // Srz(s) | gin(s) | ghn(s) | gh1(s+1)  — 112 n-tiles, heavy interleaved
        gemm3<<<dim3(8, 112), 256, 0, stream>>>(hcat, Wcat2, Cbuf, -1);
        pw_fused<<<dim3(BB / 2), 1024, 0, stream>>>(Cbuf, h1, h2, hcat,
                                                    note, velc, Wt1,
                                                    b_ih1, b_hh1, b_ih2, b_hh2,
                                                    W_out, b_out, out, s);
    }
}

// Round 15
// 1780.553 us; speedup vs baseline: 1.3428x; 1.3428x over previous
//
#include <hip/hip_runtime.h>
#include <hip/hip_bf16.h>

#define HD 1024
#define BB 512
#define SS 64
#define N3 3072
#define NC 9216      // Cbuf cols (bf16): gi2 | gh1 | gh2
#define ND 9
#define VC 4
#define KI 832       // padded K for init GEMM (784 -> 13*64)

typedef __attribute__((ext_vector_type(8))) short bf16x8;
typedef __attribute__((ext_vector_type(4))) float f32x4;

__device__ __forceinline__ ushort f2b(float f) {
    unsigned u = __builtin_bit_cast(unsigned, f);
    u += 0x7fffu + ((u >> 16) & 1u);          // round-to-nearest-even
    return (ushort)(u >> 16);
}

__device__ __forceinline__ float b2f(ushort u) {
    unsigned x = ((unsigned)u) << 16;
    return __builtin_bit_cast(float, x);
}

__device__ __forceinline__ float sigf(float x) {
    return 1.f / (1.f + __expf(-x));
}

__device__ __forceinline__ void gld_lds16(const void* g, void* l) {
    __builtin_amdgcn_global_load_lds(
        (const __attribute__((address_space(1))) unsigned int*)g,
        (__attribute__((address_space(3))) unsigned int*)l, 16, 0, 0);
}

// ============================================================================
// prep kernels (round-12 exact)
// ============================================================================
__global__ __launch_bounds__(256) void prep_w(
    const float* __restrict__ Wih2, const float* __restrict__ Whh1,
    const float* __restrict__ Whh2, ushort* __restrict__ Wcat)
{
    const int row = blockIdx.x;
    const float* src = row < 3072 ? Wih2 + (size_t)row * HD
                     : row < 6144 ? Whh1 + (size_t)(row - 3072) * HD
                                  : Whh2 + (size_t)(row - 6144) * HD;
    const int c = threadIdx.x * 4;
    float4 v = *(const float4*)(src + c);
    ushort4 o;
    o.x = f2b(v.x); o.y = f2b(v.y); o.z = f2b(v.z); o.w = f2b(v.w);
    *(ushort4*)(Wcat + (size_t)row * HD + c) = o;
}

__global__ __launch_bounds__(256) void prep_wt1(
    const float* __restrict__ Wih1, float* __restrict__ Wt1)
{
    const int g = blockIdx.x * 256 + threadIdx.x;
    #pragma unroll
    for (int c = 0; c < 22; ++c)
        Wt1[c * N3 + g] = Wih1[(size_t)g * 22 + c];
}

__global__ __launch_bounds__(256) void prep_acat(
    const float* __restrict__ z, const float* __restrict__ ne,
    const float* __restrict__ gc, ushort* __restrict__ Acat)
{
    const int b = blockIdx.x;
    const int t = threadIdx.x;
    if (t >= 208) return;
    const int c = t * 4;
    float4 v = make_float4(0.f, 0.f, 0.f, 0.f);
    if (c < 256)      v = *(const float4*)(z  + (size_t)b * 256 + c);
    else if (c < 768) v = *(const float4*)(ne + (size_t)b * 512 + (c - 256));
    else if (c < 784) v = *(const float4*)(gc + (size_t)b * 16  + (c - 768));
    ushort4 o;
    o.x = f2b(v.x); o.y = f2b(v.y); o.z = f2b(v.z); o.w = f2b(v.w);
    *(ushort4*)(Acat + (size_t)b * KI + c) = o;
}

__global__ __launch_bounds__(256) void prep_win(
    const float* __restrict__ W_in, ushort* __restrict__ W_inb)
{
    const int r = blockIdx.x;
    const int t = threadIdx.x;
    if (t >= 208) return;
    const int c = t * 4;
    ushort4 o = {0, 0, 0, 0};
    if (c < 784) {
        float4 v = *(const float4*)(W_in + (size_t)r * 784 + c);
        o.x = f2b(v.x); o.y = f2b(v.y); o.z = f2b(v.z); o.w = f2b(v.w);
    }
    *(ushort4*)(W_inb + (size_t)r * KI + c) = o;
}

// ============================================================================
// k_init: h1 = tanh(Acat @ W_inb^T + b_in). BK=64 dbuf (verified R9-R12).
// ============================================================================
__global__ __launch_bounds__(256) void k_init(
    const ushort* __restrict__ Acat, const ushort* __restrict__ W_inb,
    const float* __restrict__ b_in, float* __restrict__ h1, ushort* __restrict__ h1b)
{
    __shared__ __align__(16) ushort As[2 * 4096];
    __shared__ __align__(16) ushort Bs[2 * 4096];
    const int t = blockIdx.x;
    const int nt = t >> 3, mt = t & 7;

    const int tid = threadIdx.x;
    const int w = tid >> 6, l = tid & 63;
    const int lr = l >> 3;
    const int sw = ((l & 7) ^ lr) << 3;

    const ushort* Ag0 = Acat + ((size_t)(mt << 6) + 16 * w + lr) * KI + sw;
    const ushort* Ag1 = Ag0 + 8 * KI;
    const ushort* Bg0 = W_inb + ((size_t)(nt << 6) + 16 * w + lr) * KI + sw;
    const ushort* Bg1 = Bg0 + 8 * KI;
    const int o0 = (16 * w) * 64, o1 = (16 * w + 8) * 64;

    gld_lds16(Ag0, As + o0); gld_lds16(Ag1, As + o1);
    gld_lds16(Bg0, Bs + o0); gld_lds16(Bg1, Bs + o1);

    const int wm = (w >> 1) << 5, wn = (w & 1) << 5;
    const int fr = l & 15, fc = l >> 4;
    const int ra0 = wm + fr, ra1 = wm + 16 + fr;
    const int rb0 = wn + fr, rb1 = wn + 16 + fr;

    f32x4 acc[2][2] = {};
    for (int kt = 0; kt < 13; ++kt) {
        const int cb = (kt & 1) << 12;
        __syncthreads();
        if (kt + 1 < 13) {
            const int nb = ((kt + 1) & 1) << 12;
            const int ko = (kt + 1) << 6;
            gld_lds16(Ag0 + ko, As + nb + o0);
            gld_lds16(Ag1 + ko, As + nb + o1);
            gld_lds16(Bg0 + ko, Bs + nb + o0);
            gld_lds16(Bg1 + ko, Bs + nb + o1);
        }
        #pragma unroll
        for (int kk = 0; kk < 2; ++kk) {
            const int c = (kk << 2) + fc;
            bf16x8 a0 = *(const bf16x8*)(As + cb + ra0 * 64 + ((c ^ (ra0 & 7)) << 3));
            bf16x8 a1 = *(const bf16x8*)(As + cb + ra1 * 64 + ((c ^ (ra1 & 7)) << 3));
            bf16x8 b0 = *(const bf16x8*)(Bs + cb + rb0 * 64 + ((c ^ (rb0 & 7)) << 3));
            bf16x8 b1 = *(const bf16x8*)(Bs + cb + rb1 * 64 + ((c ^ (rb1 & 7)) << 3));
            acc[0][0] = __builtin_amdgcn_mfma_f32_16x16x32_bf16(a0, b0, acc[0][0], 0, 0, 0);
            acc[0][1] = __builtin_amdgcn_mfma_f32_16x16x32_bf16(a0, b1, acc[0][1], 0, 0, 0);
            acc[1][0] = __builtin_amdgcn_mfma_f32_16x16x32_bf16(a1, b0, acc[1][0], 0, 0, 0);
            acc[1][1] = __builtin_amdgcn_mfma_f32_16x16x32_bf16(a1, b1, acc[1][1], 0, 0, 0);
        }
    }

    const int row0 = (mt << 6) + wm;
    const int col0 = (nt << 6) + wn + fr;
    const float b0v = b_in[col0], b1v = b_in[col0 + 16];
    #pragma unroll
    for (int i = 0; i < 2; ++i) {
        #pragma unroll
        for (int r = 0; r < 4; ++r) {
            const int row = row0 + i * 16 + fc * 4 + r;
            const float v0 = tanhf(acc[i][0][r] + b0v);
            const float v1 = tanhf(acc[i][1][r] + b1v);
            h1[(size_t)row * HD + col0]       = v0;
            h1b[(size_t)row * HD + col0]      = f2b(v0);
            h1[(size_t)row * HD + col0 + 16]  = v1;
            h1b[(size_t)row * HD + col0 + 16] = f2b(v1);
        }
    }
}

// ============================================================================
// gemm3: Cbuf(bf16)[512, 9216] = [h1b@Wih2^T | h1b@Whh1^T | h2b@Whh2^T]
// ROUND-12 EXACT inner loop; ONLY the epilogue changed: bf16 C-write
// (halves C-write traffic 18.9 -> 9.4 MB/step).
// ============================================================================
__global__ __launch_bounds__(256) void gemm3(
    const ushort* __restrict__ h1b, const ushort* __restrict__ h2b,
    const ushort* __restrict__ Wcat, ushort* __restrict__ Cbuf, int ntb)
{
    __shared__ __align__(16) ushort As[4096];   // [64][64] linear
    __shared__ __align__(16) ushort Ws[4096];

    const int flat = blockIdx.x + (blockIdx.y << 3);
    const int id   = (flat & 7) * gridDim.y + (flat >> 3);
    const int bm   = (id & 7) << 6;
    const int nt   = (id >> 3) + ntb;          // global n-tile 0..143

    const ushort* Amat = (nt < 96) ? h1b : h2b;
    const ushort* W    = Wcat + (size_t)(nt << 6) * HD;

    const int tid = threadIdx.x;
    const int w   = tid >> 6;
    const int l   = tid & 63;

    const int srow = l >> 3;
    const int sch  = ((l & 7) ^ srow) << 3;
    const ushort* Ag0 = Amat + (size_t)(bm + 16 * w + srow) * HD + sch;
    const ushort* Ag1 = Ag0 + 8 * HD;
    const ushort* Wg0 = W + (size_t)(16 * w + srow) * HD + sch;
    const ushort* Wg1 = Wg0 + 8 * HD;
    ushort* Al0 = As + (16 * w) * 64;
    ushort* Al1 = As + (16 * w + 8) * 64;
    ushort* Wl0 = Ws + (16 * w) * 64;
    ushort* Wl1 = Ws + (16 * w + 8) * 64;

    const int wm = (w >> 1) << 5;
    const int wn = (w & 1) << 5;
    const int fr = l & 15;
    const int fc = l >> 4;

    const int ra0 = wm + fr,  ra1 = wm + 16 + fr;
    const int rb0 = wn + fr,  rb1 = wn + 16 + fr;

    f32x4 acc00 = {0.f,0.f,0.f,0.f}, acc01 = {0.f,0.f,0.f,0.f};
    f32x4 acc10 = {0.f,0.f,0.f,0.f}, acc11 = {0.f,0.f,0.f,0.f};

    for (int kt = 0; kt < 16; ++kt) {
        const int ko = kt << 6;
        __syncthreads();
        gld_lds16(Ag0 + ko, Al0);
        gld_lds16(Ag1 + ko, Al1);
        gld_lds16(Wg0 + ko, Wl0);
        gld_lds16(Wg1 + ko, Wl1);
        __syncthreads();
        #pragma unroll
        for (int kk = 0; kk < 2; ++kk) {
            const int c = (kk << 2) + fc;
            bf16x8 a0 = *(const bf16x8*)(As + ra0 * 64 + ((c ^ (ra0 & 7)) << 3));
            bf16x8 a1 = *(const bf16x8*)(As + ra1 * 64 + ((c ^ (ra1 & 7)) << 3));
            bf16x8 b0 = *(const bf16x8*)(Ws + rb0 * 64 + ((c ^ (rb0 & 7)) << 3));
            bf16x8 b1 = *(const bf16x8*)(Ws + rb1 * 64 + ((c ^ (rb1 & 7)) << 3));
            acc00 = __builtin_amdgcn_mfma_f32_16x16x32_bf16(a0, b0, acc00, 0, 0, 0);
            acc01 = __builtin_amdgcn_mfma_f32_16x16x32_bf16(a0, b1, acc01, 0, 0, 0);
            acc10 = __builtin_amdgcn_mfma_f32_16x16x32_bf16(a1, b0, acc10, 0, 0, 0);
            acc11 = __builtin_amdgcn_mfma_f32_16x16x32_bf16(a1, b1, acc11, 0, 0, 0);
        }
    }

    const int bn = nt << 6;
    ushort* Cw = Cbuf + (size_t)(bm + wm) * NC + bn + wn;
    #pragma unroll
    for (int r = 0; r < 4; ++r) {
        const size_t ro0 = (size_t)(fc * 4 + r) * NC;
        const size_t ro1 = (size_t)(16 + fc * 4 + r) * NC;
        Cw[ro0 + fr]      = f2b(acc00[r]);
        Cw[ro0 + 16 + fr] = f2b(acc01[r]);
        Cw[ro1 + fr]      = f2b(acc10[r]);
        Cw[ro1 + 16 + fr] = f2b(acc11[r]);
    }
}

// ============================================================================
// gru1_first: step-0 GRU1 (out_prev = 0); writes h1,h1b and copies to h2,h2b.
// grid (512) x 1024 threads.  Gates read as bf16.
// ============================================================================
__global__ __launch_bounds__(1024) void gru1_first(
    const ushort* __restrict__ Cbuf, float* __restrict__ h1, ushort* __restrict__ h1b,
    float* __restrict__ h2, ushort* __restrict__ h2b,
    const float* __restrict__ note, const float* __restrict__ velc,
    const float* __restrict__ Wt1, const float* __restrict__ b_ih1,
    const float* __restrict__ b_hh1)
{
    __shared__ float inp[22];
    const int b = blockIdx.x;
    const int j = threadIdx.x;

    if (j < 22) {
        float v = 0.f;
        if (j >= 9 && j < 18) v = note[(size_t)b * (SS * ND) + (j - 9)];
        else if (j >= 18)     v = velc[(size_t)b * (SS * VC) + (j - 18)];
        inp[j] = v;
    }
    __syncthreads();

    float ir = b_ih1[j], iz = b_ih1[HD + j], inn = b_ih1[2 * HD + j];
    #pragma unroll
    for (int c = 0; c < 22; ++c) {
        const float x = inp[c];
        const float* wr = Wt1 + c * N3;
        ir  = fmaf(x, wr[j],          ir);
        iz  = fmaf(x, wr[HD + j],     iz);
        inn = fmaf(x, wr[2 * HD + j], inn);
    }

    const ushort* g = Cbuf + (size_t)b * NC + N3;     // gh1 section
    const float hr = b2f(g[j])          + b_hh1[j];
    const float hz = b2f(g[HD + j])     + b_hh1[HD + j];
    const float hn = b2f(g[2 * HD + j]) + b_hh1[2 * HD + j];

    const float rg = sigf(ir + hr);
    const float zg = sigf(iz + hz);
    const float n  = tanhf(inn + rg * hn);
    const float hnew = (1.f - zg) * n + zg * h1[(size_t)b * HD + j];
    const ushort hb = f2b(hnew);
    h1[(size_t)b * HD + j]  = hnew;
    h1b[(size_t)b * HD + j] = hb;
    h2[(size_t)b * HD + j]  = hnew;
    h2b[(size_t)b * HD + j] = hb;
}

// ============================================================================
// pw_fused(step): per block TWO batch rows (grid 256 x 1024 thr).
// GRU2 -> h2,h2b ; out[step] ; GRU1(step+1) -> h1,h1b.  Round-12 structure;
// gate reads are bf16 (halves gate-read traffic).
// ============================================================================
__global__ __launch_bounds__(1024) void pw_fused(
    const ushort* __restrict__ Cbuf, float* __restrict__ h1, ushort* __restrict__ h1b,
    float* __restrict__ h2, ushort* __restrict__ h2b,
    const float* __restrict__ note, const float* __restrict__ velc,
    const float* __restrict__ Wt1,
    const float* __restrict__ b_ih1, const float* __restrict__ b_hh1,
    const float* __restrict__ b_ih2, const float* __restrict__ b_hh2,
    const float* __restrict__ W_out, const float* __restrict__ b_out,
    float* __restrict__ dout, int step)
{
    __shared__ float hs[2][HD];
    __shared__ float inp[2][22];
    const int j  = threadIdx.x;
    const int b0 = blockIdx.x * 2;

    // stage next-step note/velc for both rows
    if (step + 1 < SS && j < 64) {
        const int r = j >> 5, c = j & 31;
        const int b = b0 + r;
        if (c >= 9 && c < 22)
            inp[r][c] = (c < 18) ? note[(size_t)b * (SS * ND) + (step + 1) * ND + (c - 9)]
                                 : velc[(size_t)b * (SS * VC) + (step + 1) * VC + (c - 18)];
    }

    const float bir = b_ih2[j],          bhr = b_hh2[j];
    const float biz = b_ih2[HD + j],     bhz = b_hh2[HD + j];
    const float bin = b_ih2[2 * HD + j], bhn = b_hh2[2 * HD + j];

    #pragma unroll
    for (int r = 0; r < 2; ++r) {
        const int b = b0 + r;
        const ushort* gi = Cbuf + (size_t)b * NC;          // gi2
        const ushort* gh = gi + 2 * N3;                    // gh2
        const float ir  = b2f(gi[j]) + bir,          hr = b2f(gh[j]) + bhr;
        const float iz  = b2f(gi[HD + j]) + biz,     hz = b2f(gh[HD + j]) + bhz;
        const float inn = b2f(gi[2 * HD + j]) + bin, hn = b2f(gh[2 * HD + j]) + bhn;
        const float rg = sigf(ir + hr);
        const float zg = sigf(iz + hz);
        const float n  = tanhf(inn + rg * hn);
        const float hnew = (1.f - zg) * n + zg * h2[(size_t)b * HD + j];
        h2[(size_t)b * HD + j]  = hnew;
        h2b[(size_t)b * HD + j] = f2b(hnew);
        hs[r][j] = hnew;
    }
    __syncthreads();

    // out[b, step, :] — wave w: row r = w&1, dots d = (w>>1) and (w>>1)+8
    const int w = j >> 6, t = j & 63;
    {
        const int r = w & 1, b = b0 + r;
        #pragma unroll
        for (int dd = 0; dd < 2; ++dd) {
            const int d = (w >> 1) + dd * 8;
            if (d < ND) {
                float a = 0.f;
                const float* wr = W_out + (size_t)d * HD;
                #pragma unroll
                for (int k = 0; k < HD / 64; ++k)
                    a = fmaf(hs[r][t + k * 64], wr[t + k * 64], a);
                #pragma unroll
                for (int off = 32; off > 0; off >>= 1) a += __shfl_down(a, off);
                if (t == 0) {
                    const float o = sigf(a + b_out[d]);
                    dout[(size_t)b * (SS * ND) + step * ND + d] = o;
                    inp[r][d] = o;
                }
            }
        }
    }
    __syncthreads();

    // GRU1 for step+1, both rows; Wt1 read once per thread
    if (step + 1 < SS) {
        float xir[2], xiz[2], xinn[2];
        #pragma unroll
        for (int r = 0; r < 2; ++r) {
            xir[r] = b_ih1[j]; xiz[r] = b_ih1[HD + j]; xinn[r] = b_ih1[2 * HD + j];
        }
        #pragma unroll
        for (int c = 0; c < 22; ++c) {
            const float w0 = Wt1[c * N3 + j];
            const float w1 = Wt1[c * N3 + HD + j];
            const float w2 = Wt1[c * N3 + 2 * HD + j];
            #pragma unroll
            for (int r = 0; r < 2; ++r) {
                const float x = inp[r][c];
                xir[r]  = fmaf(x, w0, xir[r]);
                xiz[r]  = fmaf(x, w1, xiz[r]);
                xinn[r] = fmaf(x, w2, xinn[r]);
            }
        }
        #pragma unroll
        for (int r = 0; r < 2; ++r) {
            const int b = b0 + r;
            const ushort* g1 = Cbuf + (size_t)b * NC + N3;  // gh1 (for step+1)
            const float hr1 = b2f(g1[j])          + b_hh1[j];
            const float hz1 = b2f(g1[HD + j])     + b_hh1[HD + j];
            const float hn1 = b2f(g1[2 * HD + j]) + b_hh1[2 * HD + j];
            const float rg1 = sigf(xir[r] + hr1);
            const float zg1 = sigf(xiz[r] + hz1);
            const float n1  = tanhf(xinn[r] + rg1 * hn1);
            const float h1new = (1.f - zg1) * n1 + zg1 * h1[(size_t)b * HD + j];
            h1[(size_t)b * HD + j]  = h1new;
            h1b[(size_t)b * HD + j] = f2b(h1new);
        }
    }
}

// ============================================================================
extern "C" void kernel_launch(void* const* d_in, const int* in_sizes, int n_in,
                              void* d_out, int out_size, void* d_ws, size_t ws_size,
                              hipStream_t stream)
{
    const float* z     = (const float*)d_in[0];
    const float* ne    = (const float*)d_in[1];
    const float* note  = (const float*)d_in[3];
    const float* velc  = (const float*)d_in[4];
    const float* gc    = (const float*)d_in[5];
    const float* W_in  = (const float*)d_in[6];
    const float* b_in  = (const float*)d_in[7];
    const float* W_ih1 = (const float*)d_in[8];
    const float* W_hh1 = (const float*)d_in[9];
    const float* b_ih1 = (const float*)d_in[10];
    const float* b_hh1 = (const float*)d_in[11];
    const float* W_ih2 = (const float*)d_in[12];
    const float* W_hh2 = (const float*)d_in[13];
    const float* b_ih2 = (const float*)d_in[14];
    const float* b_hh2 = (const float*)d_in[15];
    const float* W_out = (const float*)d_in[16];
    const float* b_out = (const float*)d_in[17];
    float* out = (float*)d_out;

    // workspace layout (~35 MB)
    float*  h1   = (float*)d_ws;                     // [512*1024] f32
    float*  h2   = h1 + BB * HD;                     // [512*1024] f32
    float*  Wt1  = h2 + BB * HD;                     // [22*3072]  f32
    ushort* Cbuf = (ushort*)(Wt1 + 22 * N3);         // [512*9216] bf16
    ushort* h1b  = Cbuf + (size_t)BB * NC;           // [512*1024] bf16
    ushort* h2b  = h1b + BB * HD;                    // [512*1024] bf16
    ushort* Wcat = h2b + BB * HD;                    // [9216*1024] bf16
    // init-only buffers aliased into Cbuf (consumed before Cbuf is written)
    ushort* Acat  = Cbuf;                            // [512*832]
    ushort* W_inb = Acat + (size_t)BB * KI;          // [1024*832]

    prep_w   <<<dim3(NC), 256, 0, stream>>>(W_ih2, W_hh1, W_hh2, Wcat);
    prep_wt1 <<<dim3(12), 256, 0, stream>>>(W_ih1, Wt1);
    prep_acat<<<dim3(BB), 256, 0, stream>>>(z, ne, gc, Acat);
    prep_win <<<dim3(HD), 256, 0, stream>>>(W_in, W_inb);

    k_init<<<dim3(128), 256, 0, stream>>>(Acat, W_inb, b_in, h1, h1b);

    // prologue: gh1(0)  (n-tiles 48..95)
    gemm3<<<dim3(8, 48), 256, 0, stream>>>(h1b, h2b, Wcat, Cbuf, 48);
    gru1_first<<<dim3(BB), 1024, 0, stream>>>(Cbuf, h1, h1b, h2, h2b,
                                              note, velc, Wt1, b_ih1, b_hh1);

    for (int s = 0; s < SS; ++s) {
        // gi2(s) | gh1(s+1) | gh2(s)
        gemm3<<<dim3(8, 144), 256, 0, stream>>>(h1b, h2b, Wcat, Cbuf, 0);
        pw_fused<<<dim3(BB / 2), 1024, 0, stream>>>(Cbuf, h1, h1b, h2, h2b,
                                                    note, velc, Wt1,
                                                    b_ih1, b_hh1, b_ih2, b_hh2,
                                                    W_out, b_out, out, s);
    }
}